// Round 6
// baseline (14260.924 us; speedup 1.0000x reference)
//
#include <hip/hip_runtime.h>
#include <hip/hip_bf16.h>
#include <math.h>

#define IGNORE_INDEX (-100)

typedef __attribute__((ext_vector_type(8))) __bf16 bf16x8;
typedef __attribute__((ext_vector_type(8))) unsigned short u16x8;
typedef __attribute__((ext_vector_type(4))) float f32x4;

static constexpr int B_ = 4, S_ = 2048, H_ = 4096, V_ = 32000;
static constexpr int N_ = B_ * (S_ - 1);      // 8188 rows after causal shift
static constexpr int NPAD = 8192;             // padded rows
static constexpr int BM = 256, BN = 256, BK = 32;
static constexpr int NVB = V_ / BN;           // 125 v-blocks
static constexpr int NRB = NPAD / BM;         // 32 row-blocks
static constexpr int NKT = H_ / BK;           // 128 K-tiles
static constexpr int NWG = NVB * NRB;         // 4000 blocks

__device__ __forceinline__ unsigned short f2bf(float f) {
    unsigned int u = __float_as_uint(f);
    unsigned int r = (u + 0x7FFFu + ((u >> 16) & 1u)) >> 16;
    return (unsigned short)r;
}

__device__ __forceinline__ bf16x8 as_bf16x8(u16x8 v) {
    return __builtin_bit_cast(bf16x8, v);
}

__device__ __forceinline__ void gload16(const unsigned short* src, unsigned short* ldst) {
    __builtin_amdgcn_global_load_lds(
        (const __attribute__((address_space(1))) unsigned int*)src,
        (__attribute__((address_space(3))) unsigned int*)ldst, 16, 0, 0);
}

// ---------- convert hidden_states (causal-shifted) to bf16, pad to NPAD rows ----------
__global__ void conv_hs_kernel(const float* __restrict__ hs, unsigned short* __restrict__ A) {
    int idx = blockIdx.x * blockDim.x + threadIdx.x;   // one thread per 8 elements
    const int W8 = H_ / 8;                             // 512
    if (idx >= NPAD * W8) return;
    int row = idx / W8;
    int h8  = (idx - row * W8) * 8;
    u16x8 out;
    if (row < N_) {
        int b = row / (S_ - 1);
        int s = row - b * (S_ - 1);
        const float* src = hs + (size_t)(b * S_ + s) * H_ + h8;
        f32x4 v0 = *(const f32x4*)(src);
        f32x4 v1 = *(const f32x4*)(src + 4);
        out[0] = f2bf(v0.x); out[1] = f2bf(v0.y); out[2] = f2bf(v0.z); out[3] = f2bf(v0.w);
        out[4] = f2bf(v1.x); out[5] = f2bf(v1.y); out[6] = f2bf(v1.z); out[7] = f2bf(v1.w);
    } else {
        out = (u16x8)0;
    }
    *(u16x8*)(A + (size_t)row * H_ + h8) = out;
}

// ---------- convert lm_head weight to bf16 ----------
__global__ void conv_w_kernel(const float* __restrict__ w, unsigned short* __restrict__ Wb) {
    int idx = blockIdx.x * blockDim.x + threadIdx.x;   // one thread per 8 elements
    const int W8 = H_ / 8;
    if (idx >= V_ * W8) return;
    int row = idx / W8;
    int h8  = (idx - row * W8) * 8;
    const float* src = w + (size_t)row * H_ + h8;
    f32x4 v0 = *(const f32x4*)(src);
    f32x4 v1 = *(const f32x4*)(src + 4);
    u16x8 out;
    out[0] = f2bf(v0.x); out[1] = f2bf(v0.y); out[2] = f2bf(v0.z); out[3] = f2bf(v0.w);
    out[4] = f2bf(v1.x); out[5] = f2bf(v1.y); out[6] = f2bf(v1.z); out[7] = f2bf(v1.w);
    *(u16x8*)(Wb + (size_t)row * H_ + h8) = out;
}

// ---------- 256x256 8-wave GEMM, 2 blocks/CU (64 KiB LDS), fused partial LSE ----------
// LDS per buffer per matrix: logical [256 rows][32 cols] bf16, row stride 64 B.
// physical byte = logical byte ^ (((row>>1)&3)<<4).  Bank-group = 4*(row&1) + slot, and
// row&1 is already in the group index via the 64B stride, so the swizzle uses row bits
// 1..2: every 16-lane ds_read_b128 cohort spreads exactly 2 lanes/bank-group (0 conflicts,
// verified round 5).  Occupancy is the lever this round: 2 LDS buffers (64 KiB) give
// 2 blocks/CU; the per-tile vmcnt(0) drain of one block overlaps the other block's MFMA
// phases (m97/m114 wave-level co-scheduling), instead of relying on intra-block depth.
__global__ __launch_bounds__(512, 4) void gemm_lse_kernel(
        const unsigned short* __restrict__ A,   // [NPAD][H] bf16
        const unsigned short* __restrict__ Wb,  // [V][H] bf16
        const int* __restrict__ labels,         // [B][S]
        float* __restrict__ partial_m,          // [NPAD][NVB]
        float* __restrict__ partial_s,          // [NPAD][NVB]
        float* __restrict__ label_logit)        // [NPAD]
{
    __shared__ unsigned short lds[2][2][BM * BK];   // [buf][A=0/B=1], 2 x 32 KiB = 64 KiB

    const int tid  = threadIdx.x;
    const int lane = tid & 63;
    const int wid  = tid >> 6;
    const int wr   = wid >> 2;      // 0..1: row half
    const int wc   = wid & 3;       // 0..3: col quarter
    const int lq   = lane & 15;
    const int lr   = lane >> 4;

    // bijective XCD swizzle (NWG % 8 == 0): each XCD gets 500 consecutive tiles
    int lin = blockIdx.x;
    int swz = (lin & 7) * (NWG / 8) + (lin >> 3);
    const int rb = swz / NVB;
    const int vb = swz - rb * NVB;

    const unsigned short* Abase = A  + (size_t)rb * BM * H_;
    const unsigned short* Bbase = Wb + (size_t)vb * BN * H_;

    // ds_read physical byte offsets (one b128 per MFMA operand; full 32-col row)
    int pA[8], pB[4];
    #pragma unroll
    for (int m = 0; m < 8; ++m) {
        int r = wr * 128 + m * 16 + lq;
        pA[m] = r * 64 + ((lr * 16) ^ (((r >> 1) & 3) << 4));
    }
    #pragma unroll
    for (int n = 0; n < 4; ++n) {
        int r = wc * 64 + n * 16 + lq;
        pB[n] = r * 64 + ((lr * 16) ^ (((r >> 1) & 3) << 4));
    }

    // staging: dest physical is linear (gload_lds writes base+lane*16); per-lane global
    // source is inverse-swizzled (same involution, bits 4-5; row bits 6+ unaffected).
    int rowA[2], colA[2], rowB[2], colB[2];
    #pragma unroll
    for (int i = 0; i < 2; ++i) {
        int q = i * 8192 + wid * 1024 + lane * 16;   // physical
        int b = q ^ (((q >> 7) & 3) << 4);           // logical
        rowA[i] = b >> 6; colA[i] = (b & 63) >> 1;
        rowB[i] = b >> 6; colB[i] = (b & 63) >> 1;
    }

    f32x4 acc[8][4] = {};

    // ---------- prologue: stage K-tile 0 into buf 0 ----------
    {
        unsigned short* sA = &lds[0][0][0];
        unsigned short* sB = &lds[0][1][0];
        #pragma unroll
        for (int i = 0; i < 2; ++i)
            gload16(Abase + (size_t)rowA[i] * H_ + colA[i],
                    (unsigned short*)((char*)sA + i * 8192 + wid * 1024));
        #pragma unroll
        for (int i = 0; i < 2; ++i)
            gload16(Bbase + (size_t)rowB[i] * H_ + colB[i],
                    (unsigned short*)((char*)sB + i * 8192 + wid * 1024));
    }
    asm volatile("s_waitcnt vmcnt(0)" ::: "memory");
    __builtin_amdgcn_s_barrier();

#define RD(tile, off) (*(const u16x8*)((const char*)(tile) + (off)))
#define MF(af, bf, c4) __builtin_amdgcn_mfma_f32_16x16x32_bf16(as_bf16x8(af), as_bf16x8(bf), c4, 0, 0, 0)
#define MFMA16(MO) do { \
    acc[MO+0][0]=MF(a0,b0,acc[MO+0][0]); acc[MO+0][1]=MF(a0,b1,acc[MO+0][1]); \
    acc[MO+0][2]=MF(a0,b2,acc[MO+0][2]); acc[MO+0][3]=MF(a0,b3,acc[MO+0][3]); \
    acc[MO+1][0]=MF(a1,b0,acc[MO+1][0]); acc[MO+1][1]=MF(a1,b1,acc[MO+1][1]); \
    acc[MO+1][2]=MF(a1,b2,acc[MO+1][2]); acc[MO+1][3]=MF(a1,b3,acc[MO+1][3]); \
    acc[MO+2][0]=MF(a2,b0,acc[MO+2][0]); acc[MO+2][1]=MF(a2,b1,acc[MO+2][1]); \
    acc[MO+2][2]=MF(a2,b2,acc[MO+2][2]); acc[MO+2][3]=MF(a2,b3,acc[MO+2][3]); \
    acc[MO+3][0]=MF(a3,b0,acc[MO+3][0]); acc[MO+3][1]=MF(a3,b1,acc[MO+3][1]); \
    acc[MO+3][2]=MF(a3,b2,acc[MO+3][2]); acc[MO+3][3]=MF(a3,b3,acc[MO+3][3]); \
} while (0)
#define PHASE_MID() do { \
    __builtin_amdgcn_s_barrier(); \
    asm volatile("s_waitcnt lgkmcnt(0)" ::: "memory"); \
    __builtin_amdgcn_sched_barrier(0); \
    __builtin_amdgcn_s_setprio(1); } while (0)

    for (int T = 0; T < NKT; ++T) {
        const int cur = T & 1;
        const unsigned short* tA = &lds[cur][0][0];
        const unsigned short* tB = &lds[cur][1][0];
        unsigned short* sA = &lds[cur ^ 1][0][0];
        unsigned short* sB = &lds[cur ^ 1][1][0];
        const int kn = (T + 1) * BK;
        const bool pre = (T + 1 < NKT);
        u16x8 a0, a1, a2, a3, b0, b1, b2, b3;

        // ---- phase 0: issue ALL stages for T+1 (max cover before the boundary drain);
        //      read A m0-3 + B; MFMA upper half
        if (pre) {
            #pragma unroll
            for (int i = 0; i < 2; ++i)
                gload16(Abase + (size_t)rowA[i] * H_ + kn + colA[i],
                        (unsigned short*)((char*)sA + i * 8192 + wid * 1024));
            #pragma unroll
            for (int i = 0; i < 2; ++i)
                gload16(Bbase + (size_t)rowB[i] * H_ + kn + colB[i],
                        (unsigned short*)((char*)sB + i * 8192 + wid * 1024));
        }
        a0 = RD(tA, pA[0]); a1 = RD(tA, pA[1]); a2 = RD(tA, pA[2]); a3 = RD(tA, pA[3]);
        b0 = RD(tB, pB[0]); b1 = RD(tB, pB[1]); b2 = RD(tB, pB[2]); b3 = RD(tB, pB[3]);
        PHASE_MID();
        MFMA16(0);
        __builtin_amdgcn_s_setprio(0);
        __builtin_amdgcn_s_barrier();

        // ---- phase 1: read A m4-7; MFMA lower half; boundary drain
        a0 = RD(tA, pA[4]); a1 = RD(tA, pA[5]); a2 = RD(tA, pA[6]); a3 = RD(tA, pA[7]);
        PHASE_MID();
        MFMA16(4);
        __builtin_amdgcn_s_setprio(0);
        asm volatile("s_waitcnt vmcnt(0)" ::: "memory");
        __builtin_amdgcn_s_barrier();
    }

    // ---------- epilogue: per-row max & sum-exp over this 256-col tile ----------
    __syncthreads();
    float* red_m = (float*)&lds[0][0][0];   // [4][256]
    float* red_s = red_m + 1024;            // [4][256]

    #pragma unroll
    for (int m = 0; m < 8; ++m) {
        #pragma unroll
        for (int q = 0; q < 4; ++q) {
            float mx = fmaxf(fmaxf(acc[m][0][q], acc[m][1][q]), fmaxf(acc[m][2][q], acc[m][3][q]));
            #pragma unroll
            for (int d = 1; d < 16; d <<= 1) mx = fmaxf(mx, __shfl_xor(mx, d, 64));
            float ss = __expf(acc[m][0][q] - mx) + __expf(acc[m][1][q] - mx)
                     + __expf(acc[m][2][q] - mx) + __expf(acc[m][3][q] - mx);
            #pragma unroll
            for (int d = 1; d < 16; d <<= 1) ss += __shfl_xor(ss, d, 64);
            if (lq == 0) {
                int rloc = wr * 128 + m * 16 + lr * 4 + q;
                red_m[wc * 256 + rloc] = mx;
                red_s[wc * 256 + rloc] = ss;
            }
        }
    }
    __syncthreads();
    if (tid < 256) {
        float m0 = red_m[tid], m1 = red_m[256 + tid], m2 = red_m[512 + tid], m3 = red_m[768 + tid];
        float s0 = red_s[tid], s1 = red_s[256 + tid], s2 = red_s[512 + tid], s3 = red_s[768 + tid];
        float mm = fmaxf(fmaxf(m0, m1), fmaxf(m2, m3));
        float ss = s0 * __expf(m0 - mm) + s1 * __expf(m1 - mm)
                 + s2 * __expf(m2 - mm) + s3 * __expf(m3 - mm);
        int rowg = rb * BM + tid;
        partial_m[(size_t)rowg * NVB + vb] = mm;
        partial_s[(size_t)rowg * NVB + vb] = ss;
    }

    // ---------- capture the label logit if it falls in this tile ----------
    #pragma unroll
    for (int m = 0; m < 8; ++m) {
        #pragma unroll
        for (int q = 0; q < 4; ++q) {
            int rowg = rb * BM + wr * 128 + m * 16 + lr * 4 + q;
            if (rowg < N_) {
                int bb = rowg / (S_ - 1);
                int s = rowg - bb * (S_ - 1);
                int lbl = labels[bb * S_ + s + 1];
                int ccol = lbl - (vb * BN + wc * 64);
                if (ccol >= 0 && ccol < 64 && (ccol & 15) == lq) {
                    int nsel = ccol >> 4;
                    float val;
                    if (nsel == 0)      val = acc[m][0][q];
                    else if (nsel == 1) val = acc[m][1][q];
                    else if (nsel == 2) val = acc[m][2][q];
                    else                val = acc[m][3][q];
                    label_logit[rowg] = val;
                }
            }
        }
    }
}

// ---------- per-row combine of partials -> nll ----------
__global__ void row_nll_kernel(const float* __restrict__ partial_m,
                               const float* __restrict__ partial_s,
                               const float* __restrict__ label_logit,
                               const int* __restrict__ labels,
                               float* __restrict__ nll)
{
    int row = blockIdx.x * blockDim.x + threadIdx.x;
    if (row >= N_) return;
    const float* pm = partial_m + (size_t)row * NVB;
    const float* ps = partial_s + (size_t)row * NVB;
    float mm = -INFINITY;
    for (int j = 0; j < NVB; ++j) mm = fmaxf(mm, pm[j]);
    float ss = 0.f;
    for (int j = 0; j < NVB; ++j) ss += ps[j] * expf(pm[j] - mm);
    float lse = mm + logf(ss);
    int b = row / (S_ - 1);
    int s = row - b * (S_ - 1);
    int lbl = labels[b * S_ + s + 1];
    float out = 0.f;
    if (lbl != IGNORE_INDEX) out = lse - label_logit[row];
    nll[row] = out;
}

// ---------- final mean over valid rows ----------
__global__ void final_reduce_kernel(const float* __restrict__ nll,
                                    const int* __restrict__ labels,
                                    float* __restrict__ out)
{
    __shared__ float s_sum[256];
    __shared__ float s_cnt[256];
    int tid = threadIdx.x;
    float sum = 0.f, cnt = 0.f;
    for (int row = tid; row < N_; row += 256) {
        int b = row / (S_ - 1);
        int s = row - b * (S_ - 1);
        int lbl = labels[b * S_ + s + 1];
        if (lbl != IGNORE_INDEX) { sum += nll[row]; cnt += 1.f; }
    }
    s_sum[tid] = sum; s_cnt[tid] = cnt;
    __syncthreads();
    for (int d = 128; d > 0; d >>= 1) {
        if (tid < d) { s_sum[tid] += s_sum[tid + d]; s_cnt[tid] += s_cnt[tid + d]; }
        __syncthreads();
    }
    if (tid == 0) out[0] = s_sum[0] / fmaxf(s_cnt[0], 1.f);
}

extern "C" void kernel_launch(void* const* d_in, const int* in_sizes, int n_in,
                              void* d_out, int out_size, void* d_ws, size_t ws_size,
                              hipStream_t stream) {
    const float* hs  = (const float*)d_in[0];
    const float* w   = (const float*)d_in[1];
    const int*   lbl = (const int*)d_in[2];
    float* out = (float*)d_out;

    char* ws = (char*)d_ws;
    size_t off = 0;
    unsigned short* A_bf16 = (unsigned short*)(ws + off); off += (size_t)NPAD * H_ * 2;   // 64 MB
    unsigned short* W_bf16 = (unsigned short*)(ws + off); off += (size_t)V_ * H_ * 2;     // 250 MB
    float* partial_m   = (float*)(ws + off); off += (size_t)NPAD * NVB * 4;               // 4 MB
    float* partial_s   = (float*)(ws + off); off += (size_t)NPAD * NVB * 4;               // 4 MB
    float* label_logit = (float*)(ws + off); off += (size_t)NPAD * 4;
    float* nll         = (float*)(ws + off); off += (size_t)NPAD * 4;

    {
        int total = NPAD * (H_ / 8);
        conv_hs_kernel<<<(total + 255) / 256, 256, 0, stream>>>(hs, A_bf16);
    }
    {
        int total = V_ * (H_ / 8);
        conv_w_kernel<<<(total + 255) / 256, 256, 0, stream>>>(w, W_bf16);
    }
    gemm_lse_kernel<<<NWG, 512, 0, stream>>>(A_bf16, W_bf16, lbl,
                                             partial_m, partial_s, label_logit);
    row_nll_kernel<<<(N_ + 255) / 256, 256, 0, stream>>>(partial_m, partial_s, label_logit, lbl, nll);
    final_reduce_kernel<<<1, 256, 0, stream>>>(nll, lbl, out);
}

// Round 7
// 1322.347 us; speedup vs baseline: 10.7846x; 10.7846x over previous
//
#include <hip/hip_runtime.h>
#include <math.h>

#define IGNORE_INDEX (-100)

typedef __attribute__((ext_vector_type(4))) int i32x4;
typedef __attribute__((ext_vector_type(4))) float f32x4;

static constexpr int B_ = 4, S_ = 2048, H_ = 4096, V_ = 32000;
static constexpr int N_ = B_ * (S_ - 1);      // 8188 rows after causal shift
static constexpr int NPAD = 8192;             // padded rows
static constexpr int BM = 256, BN = 256, BK = 128;
static constexpr int NVB = V_ / BN;           // 125 v-blocks
static constexpr int NRB = NPAD / BM;         // 32 row-blocks
static constexpr int NKT = H_ / BK;           // 32 K-tiles
static constexpr int NWG = NVB * NRB;         // 4000 blocks

__device__ __forceinline__ void gload16(const signed char* src, signed char* ldst) {
    __builtin_amdgcn_global_load_lds(
        (const __attribute__((address_space(1))) unsigned int*)src,
        (__attribute__((address_space(3))) unsigned int*)ldst, 16, 0, 0);
}

// ---------- per-row symmetric int8 quantization of hidden_states (causal-shifted, padded) ----------
// one block per row; 4 coalesced passes (each wave reads/writes contiguous spans)
__global__ void quant_hs_kernel(const float* __restrict__ hs,
                                signed char* __restrict__ qA, float* __restrict__ sA) {
    const int row = blockIdx.x;          // 0..NPAD-1
    const int tid = threadIdx.x;         // 256 threads
    __shared__ float red[256];
    f32x4 v0, v1, v2, v3;
    if (row < N_) {
        int b = row / (S_ - 1);
        int s = row - b * (S_ - 1);
        const float* src = hs + (size_t)(b * S_ + s) * H_;
        v0 = *(const f32x4*)(src + tid * 4 + 0 * 1024);
        v1 = *(const f32x4*)(src + tid * 4 + 1 * 1024);
        v2 = *(const f32x4*)(src + tid * 4 + 2 * 1024);
        v3 = *(const f32x4*)(src + tid * 4 + 3 * 1024);
    } else {
        v0 = v1 = v2 = v3 = (f32x4)0.f;
    }
    float amax = 0.f;
    amax = fmaxf(amax, fmaxf(fmaxf(fabsf(v0[0]), fabsf(v0[1])), fmaxf(fabsf(v0[2]), fabsf(v0[3]))));
    amax = fmaxf(amax, fmaxf(fmaxf(fabsf(v1[0]), fabsf(v1[1])), fmaxf(fabsf(v1[2]), fabsf(v1[3]))));
    amax = fmaxf(amax, fmaxf(fmaxf(fabsf(v2[0]), fabsf(v2[1])), fmaxf(fabsf(v2[2]), fabsf(v2[3]))));
    amax = fmaxf(amax, fmaxf(fmaxf(fabsf(v3[0]), fabsf(v3[1])), fmaxf(fabsf(v3[2]), fabsf(v3[3]))));
    red[tid] = amax;
    __syncthreads();
    for (int d = 128; d > 0; d >>= 1) {
        if (tid < d) red[tid] = fmaxf(red[tid], red[tid + d]);
        __syncthreads();
    }
    const float m = fmaxf(red[0], 1e-30f);
    const float inv = 127.f / m;
    unsigned int* dst = (unsigned int*)(qA + (size_t)row * H_);
#define QPACK(vv, J) do { \
    int q0 = __float2int_rn(vv[0] * inv), q1 = __float2int_rn(vv[1] * inv); \
    int q2 = __float2int_rn(vv[2] * inv), q3 = __float2int_rn(vv[3] * inv); \
    unsigned int p = (q0 & 255) | ((q1 & 255) << 8) | ((q2 & 255) << 16) | ((unsigned)(q3 & 255) << 24); \
    dst[tid + (J) * 256] = p; } while (0)
    QPACK(v0, 0); QPACK(v1, 1); QPACK(v2, 2); QPACK(v3, 3);
#undef QPACK
    if (tid == 0) sA[row] = m * (1.f / 127.f);
}

// ---------- per-row symmetric int8 quantization of lm_head weight ----------
__global__ void quant_w_kernel(const float* __restrict__ w,
                               signed char* __restrict__ qW, float* __restrict__ sW) {
    const int row = blockIdx.x;          // 0..V-1
    const int tid = threadIdx.x;
    __shared__ float red[256];
    const float* src = w + (size_t)row * H_;
    f32x4 v0 = *(const f32x4*)(src + tid * 4 + 0 * 1024);
    f32x4 v1 = *(const f32x4*)(src + tid * 4 + 1 * 1024);
    f32x4 v2 = *(const f32x4*)(src + tid * 4 + 2 * 1024);
    f32x4 v3 = *(const f32x4*)(src + tid * 4 + 3 * 1024);
    float amax = 0.f;
    amax = fmaxf(amax, fmaxf(fmaxf(fabsf(v0[0]), fabsf(v0[1])), fmaxf(fabsf(v0[2]), fabsf(v0[3]))));
    amax = fmaxf(amax, fmaxf(fmaxf(fabsf(v1[0]), fabsf(v1[1])), fmaxf(fabsf(v1[2]), fabsf(v1[3]))));
    amax = fmaxf(amax, fmaxf(fmaxf(fabsf(v2[0]), fabsf(v2[1])), fmaxf(fabsf(v2[2]), fabsf(v2[3]))));
    amax = fmaxf(amax, fmaxf(fmaxf(fabsf(v3[0]), fabsf(v3[1])), fmaxf(fabsf(v3[2]), fabsf(v3[3]))));
    red[tid] = amax;
    __syncthreads();
    for (int d = 128; d > 0; d >>= 1) {
        if (tid < d) red[tid] = fmaxf(red[tid], red[tid + d]);
        __syncthreads();
    }
    const float m = fmaxf(red[0], 1e-30f);
    const float inv = 127.f / m;
    unsigned int* dst = (unsigned int*)(qW + (size_t)row * H_);
#define QPACK(vv, J) do { \
    int q0 = __float2int_rn(vv[0] * inv), q1 = __float2int_rn(vv[1] * inv); \
    int q2 = __float2int_rn(vv[2] * inv), q3 = __float2int_rn(vv[3] * inv); \
    unsigned int p = (q0 & 255) | ((q1 & 255) << 8) | ((q2 & 255) << 16) | ((unsigned)(q3 & 255) << 24); \
    dst[tid + (J) * 256] = p; } while (0)
    QPACK(v0, 0); QPACK(v1, 1); QPACK(v2, 2); QPACK(v3, 3);
#undef QPACK
    if (tid == 0) sW[row] = m * (1.f / 127.f);
}

// ---------- 256x256 8-wave i8 GEMM (BK=128, mfma_i32_16x16x64_i8) + fused partial LSE ----------
// Round-3 structure (measured best: 4 phases/tile, 2 barriers/phase, per-tile vmcnt(0) drain),
// but int8 doubles MFMA rate and halves staging bytes -> NKT 64 -> 32, so per-tile overhead
// halves too.  LDS per buffer per matrix: [256 rows][128 cols] i8, row stride 128 B --
// identical addressing to the verified bf16 [256][64] layout: physical byte =
// r*128 + ((slot*16) ^ ((r&7)<<4)); kk half-step (logical +64B) is phys^64 (XOR commutes);
// staging source inverse-swizzled (involution on bits 4-6, row bits >=7 untouched).
// Verified 0 bank conflicts in rounds 3/5 with this exact formula.
__global__ __launch_bounds__(512, 2) void gemm_lse_kernel(
        const signed char* __restrict__ Aq,    // [NPAD][H] i8
        const signed char* __restrict__ Wq,    // [V][H] i8
        const float* __restrict__ sA,          // [NPAD]
        const float* __restrict__ sW,          // [V]
        const int* __restrict__ labels,        // [B][S]
        float* __restrict__ partial_m,         // [NPAD][NVB]
        float* __restrict__ partial_s,         // [NPAD][NVB]
        float* __restrict__ label_logit)       // [NPAD]
{
    __shared__ signed char lds[2][2][BM * BK];   // [buf][A=0/B=1], 2 x 64 KiB = 128 KiB

    const int tid  = threadIdx.x;
    const int lane = tid & 63;
    const int wid  = tid >> 6;
    const int wr   = wid >> 2;      // 0..1: row half
    const int wc   = wid & 3;       // 0..3: col quarter
    const int lq   = lane & 15;
    const int lr   = lane >> 4;

    // bijective XCD swizzle (NWG % 8 == 0)
    int lin = blockIdx.x;
    int swz = (lin & 7) * (NWG / 8) + (lin >> 3);
    const int rb = swz / NVB;
    const int vb = swz - rb * NVB;

    const signed char* Abase = Aq + (size_t)rb * BM * H_;
    const signed char* Bbase = Wq + (size_t)vb * BN * H_;

    // ds_read physical byte offsets for kk=0 (kk=1 is offset ^ 64)
    int pA[8], pB[4];
    #pragma unroll
    for (int m = 0; m < 8; ++m) {
        int r = wr * 128 + m * 16 + lq;
        pA[m] = r * 128 + ((lr * 16) ^ ((r & 7) << 4));
    }
    #pragma unroll
    for (int n = 0; n < 4; ++n) {
        int r = wc * 64 + n * 16 + lq;
        pB[n] = r * 128 + ((lr * 16) ^ ((r & 7) << 4));
    }

    // staging: linear physical dest (gload_lds = base + lane*16); inverse-swizzled source.
    // 4 gloads per thread per matrix per tile (32 KiB / 512 threads / 16 B).
    int rowS[4], colS[4];
    #pragma unroll
    for (int i = 0; i < 4; ++i) {
        int q = i * 8192 + wid * 1024 + lane * 16;   // physical
        int b = q ^ (((q >> 7) & 7) << 4);           // logical
        rowS[i] = b >> 7;
        colS[i] = b & 127;                           // i8: byte == element
    }

    i32x4 acc[8][4] = {};

    // ---------- prologue: stage K-tile 0 into buf 0 ----------
    {
        signed char* dA = &lds[0][0][0];
        signed char* dB = &lds[0][1][0];
        #pragma unroll
        for (int i = 0; i < 4; ++i)
            gload16(Abase + (size_t)rowS[i] * H_ + colS[i], dA + i * 8192 + wid * 1024);
        #pragma unroll
        for (int i = 0; i < 4; ++i)
            gload16(Bbase + (size_t)rowS[i] * H_ + colS[i], dB + i * 8192 + wid * 1024);
    }
    asm volatile("s_waitcnt vmcnt(0)" ::: "memory");
    __builtin_amdgcn_s_barrier();

#define RDI(tile, off) (*(const i32x4*)((const char*)(tile) + (off)))
#define MF(af, bf, c4) __builtin_amdgcn_mfma_i32_16x16x64_i8(af, bf, c4, 0, 0, 0)
#define MFMA16(MO) do { \
    acc[MO+0][0]=MF(a0,b0,acc[MO+0][0]); acc[MO+0][1]=MF(a0,b1,acc[MO+0][1]); \
    acc[MO+0][2]=MF(a0,b2,acc[MO+0][2]); acc[MO+0][3]=MF(a0,b3,acc[MO+0][3]); \
    acc[MO+1][0]=MF(a1,b0,acc[MO+1][0]); acc[MO+1][1]=MF(a1,b1,acc[MO+1][1]); \
    acc[MO+1][2]=MF(a1,b2,acc[MO+1][2]); acc[MO+1][3]=MF(a1,b3,acc[MO+1][3]); \
    acc[MO+2][0]=MF(a2,b0,acc[MO+2][0]); acc[MO+2][1]=MF(a2,b1,acc[MO+2][1]); \
    acc[MO+2][2]=MF(a2,b2,acc[MO+2][2]); acc[MO+2][3]=MF(a2,b3,acc[MO+2][3]); \
    acc[MO+3][0]=MF(a3,b0,acc[MO+3][0]); acc[MO+3][1]=MF(a3,b1,acc[MO+3][1]); \
    acc[MO+3][2]=MF(a3,b2,acc[MO+3][2]); acc[MO+3][3]=MF(a3,b3,acc[MO+3][3]); \
} while (0)
#define PHASE_MID() do { \
    __builtin_amdgcn_s_barrier(); \
    asm volatile("s_waitcnt lgkmcnt(0)" ::: "memory"); \
    __builtin_amdgcn_sched_barrier(0); \
    __builtin_amdgcn_s_setprio(1); } while (0)

    for (int T = 0; T < NKT; ++T) {
        const int cur = T & 1;
        const signed char* tA = &lds[cur][0][0];
        const signed char* tB = &lds[cur][1][0];
        signed char* dA = &lds[cur ^ 1][0][0];
        signed char* dB = &lds[cur ^ 1][1][0];
        const int kn = (T + 1) * BK;
        const bool pre = (T + 1 < NKT);
        i32x4 a0, a1, a2, a3, b0, b1, b2, b3;

        // ---- phase 0: stage A i=0,1 (T+1); read A m0-3 kk0 + B kk0; MFMA upper kk0
        if (pre) {
            gload16(Abase + (size_t)rowS[0] * H_ + kn + colS[0], dA + 0 * 8192 + wid * 1024);
            gload16(Abase + (size_t)rowS[1] * H_ + kn + colS[1], dA + 1 * 8192 + wid * 1024);
        }
        a0 = RDI(tA, pA[0]); a1 = RDI(tA, pA[1]); a2 = RDI(tA, pA[2]); a3 = RDI(tA, pA[3]);
        b0 = RDI(tB, pB[0]); b1 = RDI(tB, pB[1]); b2 = RDI(tB, pB[2]); b3 = RDI(tB, pB[3]);
        PHASE_MID(); MFMA16(0);
        __builtin_amdgcn_s_setprio(0);
        __builtin_amdgcn_s_barrier();

        // ---- phase 1: stage A i=2,3; read A m4-7 kk0; MFMA lower kk0
        if (pre) {
            gload16(Abase + (size_t)rowS[2] * H_ + kn + colS[2], dA + 2 * 8192 + wid * 1024);
            gload16(Abase + (size_t)rowS[3] * H_ + kn + colS[3], dA + 3 * 8192 + wid * 1024);
        }
        a0 = RDI(tA, pA[4]); a1 = RDI(tA, pA[5]); a2 = RDI(tA, pA[6]); a3 = RDI(tA, pA[7]);
        PHASE_MID(); MFMA16(4);
        __builtin_amdgcn_s_setprio(0);
        __builtin_amdgcn_s_barrier();

        // ---- phase 2: stage B i=0,1; read A m0-3 kk1 + B kk1; MFMA upper kk1
        if (pre) {
            gload16(Bbase + (size_t)rowS[0] * H_ + kn + colS[0], dB + 0 * 8192 + wid * 1024);
            gload16(Bbase + (size_t)rowS[1] * H_ + kn + colS[1], dB + 1 * 8192 + wid * 1024);
        }
        a0 = RDI(tA, pA[0] ^ 64); a1 = RDI(tA, pA[1] ^ 64); a2 = RDI(tA, pA[2] ^ 64); a3 = RDI(tA, pA[3] ^ 64);
        b0 = RDI(tB, pB[0] ^ 64); b1 = RDI(tB, pB[1] ^ 64); b2 = RDI(tB, pB[2] ^ 64); b3 = RDI(tB, pB[3] ^ 64);
        PHASE_MID(); MFMA16(0);
        __builtin_amdgcn_s_setprio(0);
        __builtin_amdgcn_s_barrier();

        // ---- phase 3: stage B i=2,3; read A m4-7 kk1; MFMA lower kk1; boundary drain
        if (pre) {
            gload16(Bbase + (size_t)rowS[2] * H_ + kn + colS[2], dB + 2 * 8192 + wid * 1024);
            gload16(Bbase + (size_t)rowS[3] * H_ + kn + colS[3], dB + 3 * 8192 + wid * 1024);
        }
        a0 = RDI(tA, pA[4] ^ 64); a1 = RDI(tA, pA[5] ^ 64); a2 = RDI(tA, pA[6] ^ 64); a3 = RDI(tA, pA[7] ^ 64);
        PHASE_MID(); MFMA16(4);
        __builtin_amdgcn_s_setprio(0);
        asm volatile("s_waitcnt vmcnt(0)" ::: "memory");
        __builtin_amdgcn_s_barrier();
    }

    // ---------- epilogue: dequant + per-row max & sum-exp over this 256-col tile ----------
    __syncthreads();
    float* red_m = (float*)&lds[0][0][0];   // [4][256]
    float* red_s = red_m + 1024;            // [4][256]

    const float* sArow = sA + rb * 256 + wr * 128;
    const float sw0 = sW[vb * 256 + wc * 64 + 0 * 16 + lq];
    const float sw1 = sW[vb * 256 + wc * 64 + 1 * 16 + lq];
    const float sw2 = sW[vb * 256 + wc * 64 + 2 * 16 + lq];
    const float sw3 = sW[vb * 256 + wc * 64 + 3 * 16 + lq];

    #pragma unroll
    for (int m = 0; m < 8; ++m) {
        f32x4 sav = *(const f32x4*)(sArow + m * 16 + lr * 4);
        #pragma unroll
        for (int q = 0; q < 4; ++q) {
            const float sa = sav[q];
            float l0 = (float)acc[m][0][q] * sa * sw0;
            float l1 = (float)acc[m][1][q] * sa * sw1;
            float l2 = (float)acc[m][2][q] * sa * sw2;
            float l3 = (float)acc[m][3][q] * sa * sw3;
            float mx = fmaxf(fmaxf(l0, l1), fmaxf(l2, l3));
            #pragma unroll
            for (int d = 1; d < 16; d <<= 1) mx = fmaxf(mx, __shfl_xor(mx, d, 64));
            float ss = __expf(l0 - mx) + __expf(l1 - mx) + __expf(l2 - mx) + __expf(l3 - mx);
            #pragma unroll
            for (int d = 1; d < 16; d <<= 1) ss += __shfl_xor(ss, d, 64);
            if (lq == 0) {
                int rloc = wr * 128 + m * 16 + lr * 4 + q;
                red_m[wc * 256 + rloc] = mx;
                red_s[wc * 256 + rloc] = ss;
            }
            // label-logit capture (already dequantized)
            int rowg = rb * BM + wr * 128 + m * 16 + lr * 4 + q;
            if (rowg < N_) {
                int bb = rowg / (S_ - 1);
                int s = rowg - bb * (S_ - 1);
                int lbl = labels[bb * S_ + s + 1];
                int ccol = lbl - (vb * BN + wc * 64);
                if (ccol >= 0 && ccol < 64 && (ccol & 15) == lq) {
                    int nsel = ccol >> 4;
                    float val;
                    if (nsel == 0)      val = l0;
                    else if (nsel == 1) val = l1;
                    else if (nsel == 2) val = l2;
                    else                val = l3;
                    label_logit[rowg] = val;
                }
            }
        }
    }
    __syncthreads();
    if (tid < 256) {
        float m0 = red_m[tid], m1 = red_m[256 + tid], m2 = red_m[512 + tid], m3 = red_m[768 + tid];
        float s0 = red_s[tid], s1 = red_s[256 + tid], s2 = red_s[512 + tid], s3 = red_s[768 + tid];
        float mm = fmaxf(fmaxf(m0, m1), fmaxf(m2, m3));
        float ss = s0 * __expf(m0 - mm) + s1 * __expf(m1 - mm)
                 + s2 * __expf(m2 - mm) + s3 * __expf(m3 - mm);
        int rowg = rb * BM + tid;
        partial_m[(size_t)rowg * NVB + vb] = mm;
        partial_s[(size_t)rowg * NVB + vb] = ss;
    }
}

// ---------- per-row combine of partials -> nll ----------
__global__ void row_nll_kernel(const float* __restrict__ partial_m,
                               const float* __restrict__ partial_s,
                               const float* __restrict__ label_logit,
                               const int* __restrict__ labels,
                               float* __restrict__ nll)
{
    int row = blockIdx.x * blockDim.x + threadIdx.x;
    if (row >= N_) return;
    const float* pm = partial_m + (size_t)row * NVB;
    const float* ps = partial_s + (size_t)row * NVB;
    float mm = -INFINITY;
    for (int j = 0; j < NVB; ++j) mm = fmaxf(mm, pm[j]);
    float ss = 0.f;
    for (int j = 0; j < NVB; ++j) ss += ps[j] * expf(pm[j] - mm);
    float lse = mm + logf(ss);
    int b = row / (S_ - 1);
    int s = row - b * (S_ - 1);
    int lbl = labels[b * S_ + s + 1];
    float out = 0.f;
    if (lbl != IGNORE_INDEX) out = lse - label_logit[row];
    nll[row] = out;
}

// ---------- final mean over valid rows ----------
__global__ void final_reduce_kernel(const float* __restrict__ nll,
                                    const int* __restrict__ labels,
                                    float* __restrict__ out)
{
    __shared__ float s_sum[256];
    __shared__ float s_cnt[256];
    int tid = threadIdx.x;
    float sum = 0.f, cnt = 0.f;
    for (int row = tid; row < N_; row += 256) {
        int b = row / (S_ - 1);
        int s = row - b * (S_ - 1);
        int lbl = labels[b * S_ + s + 1];
        if (lbl != IGNORE_INDEX) { sum += nll[row]; cnt += 1.f; }
    }
    s_sum[tid] = sum; s_cnt[tid] = cnt;
    __syncthreads();
    for (int d = 128; d > 0; d >>= 1) {
        if (tid < d) { s_sum[tid] += s_sum[tid + d]; s_cnt[tid] += s_cnt[tid + d]; }
        __syncthreads();
    }
    if (tid == 0) out[0] = s_sum[0] / fmaxf(s_cnt[0], 1.f);
}

extern "C" void kernel_launch(void* const* d_in, const int* in_sizes, int n_in,
                              void* d_out, int out_size, void* d_ws, size_t ws_size,
                              hipStream_t stream) {
    const float* hs  = (const float*)d_in[0];
    const float* w   = (const float*)d_in[1];
    const int*   lbl = (const int*)d_in[2];
    float* out = (float*)d_out;

    char* ws = (char*)d_ws;
    size_t off = 0;
    signed char* qA = (signed char*)(ws + off); off += (size_t)NPAD * H_;      // 33.5 MB
    signed char* qW = (signed char*)(ws + off); off += (size_t)V_ * H_;        // 131 MB
    float* sA          = (float*)(ws + off); off += (size_t)NPAD * 4;
    float* sW          = (float*)(ws + off); off += (size_t)V_ * 4;
    float* partial_m   = (float*)(ws + off); off += (size_t)NPAD * NVB * 4;    // 4 MB
    float* partial_s   = (float*)(ws + off); off += (size_t)NPAD * NVB * 4;    // 4 MB
    float* label_logit = (float*)(ws + off); off += (size_t)NPAD * 4;
    float* nll         = (float*)(ws + off); off += (size_t)NPAD * 4;

    quant_hs_kernel<<<NPAD, 256, 0, stream>>>(hs, qA, sA);
    quant_w_kernel<<<V_, 256, 0, stream>>>(w, qW, sW);
    gemm_lse_kernel<<<NWG, 512, 0, stream>>>(qA, qW, sA, sW, lbl,
                                             partial_m, partial_s, label_logit);
    row_nll_kernel<<<(N_ + 255) / 256, 256, 0, stream>>>(partial_m, partial_s, label_logit, lbl, nll);
    final_reduce_kernel<<<1, 256, 0, stream>>>(nll, lbl, out);
}